// Round 3
// baseline (658.777 us; speedup 1.0000x reference)
//
#include <hip/hip_runtime.h>
#include <math.h>

// KSIZE=3, STRIDE=1, RATE=2, FUSE_K=3, SCALE=10
#define CDIM 128
#define HF   128
#define WF   128
#define NP   4096   // 64*64 downsampled positions
#define NCHUNK 64   // softmax u-chunks (64 rows each)

typedef __attribute__((ext_vector_type(8))) short short8;
typedef __attribute__((ext_vector_type(16))) float f16a;
typedef float __attribute__((ext_vector_type(4), aligned(16))) f4a16;
typedef float __attribute__((ext_vector_type(4), aligned(4)))  f4u;

__device__ inline ushort f2bf(float x) {
  union { float f; unsigned u; } v; v.f = x;
  unsigned r = v.u + 0x7fff + ((v.u >> 16) & 1);
  return (ushort)(r >> 16);
}
__device__ inline float bf2f(ushort h) {
  union { unsigned u; float f; } v; v.u = ((unsigned)h) << 16; return v.f;
}

__device__ inline void gl2lds16(const ushort* g, ushort* l) {
  __builtin_amdgcn_global_load_lds((const __attribute__((address_space(1))) void*)g,
                                   (__attribute__((address_space(3))) void*)l, 16, 0, 0);
}

// ---------------------------------------------------------------------------
// prep: downsample + split fp32 -> (hi,lo) bf16 K-major cat operands, AND
// s2[p] = sum_c b_ds[c,p]^2
__global__ __launch_bounds__(256) void k_prep(const float* __restrict__ f,
                                              const float* __restrict__ b,
                                              ushort* __restrict__ fcat,
                                              ushort* __restrict__ bcat,
                                              float* __restrict__ s2) {
  int idx = blockIdx.x * 256 + threadIdx.x;   // 524288
  int c = idx & 127, pos = idx >> 7;
  int x = pos & 63, y = pos >> 6;
  int src = c * 16384 + y * 256 + x * 2;
  float fv = f[src], bv = b[src];
  ushort fh = f2bf(fv); ushort fl = f2bf(fv - bf2f(fh));
  ushort bh = f2bf(bv); ushort bl = f2bf(bv - bf2f(bh));
  size_t base = (size_t)pos * 384;
  fcat[base + c] = fh; fcat[base + 128 + c] = fl; fcat[base + 256 + c] = fh;
  bcat[base + c] = bh; bcat[base + 128 + c] = bh; bcat[base + 256 + c] = bl;
  float sq = bv * bv;
#pragma unroll
  for (int off = 32; off; off >>= 1) sq += __shfl_down(sq, off);
  __shared__ float wsum[4];
  if ((threadIdx.x & 63) == 0) wsum[threadIdx.x >> 6] = sq;
  __syncthreads();
  if (threadIdx.x == 0) s2[blockIdx.x * 2]     = wsum[0] + wsum[1];
  if (threadIdx.x == 1) s2[blockIdx.x * 2 + 1] = wsum[2] + wsum[3];
}

// merged: blocks 0..15 -> mmp[a] (mask gate at p=pi(a)); 16..31 -> rnrm[p]
__global__ __launch_bounds__(256) void k_mmpnorm(const float* __restrict__ mask,
                                                 const float* __restrict__ s2,
                                                 float* __restrict__ mmp,
                                                 float* __restrict__ rnrm) {
  int bx = blockIdx.x, t = threadIdx.x;
  if (bx < 16) {
    int a = bx * 256 + t;
    int yb = a & 63, xb = a >> 6;               // p = pi(a)
    float s = 0.f;
    for (int dy = -1; dy <= 1; ++dy)
      for (int dx = -1; dx <= 1; ++dx) {
        int y = yb + dy, x = xb + dx;
        if ((unsigned)y < 64u && (unsigned)x < 64u)
          s += mask[y * 256 + x * 2];
      }
    mmp[a] = (s == 0.0f) ? 1.0f : 0.0f;
  } else {
    int p = (bx - 16) * 256 + t;
    int xb = p & 63, yb = p >> 6;
    float s = 0.f;
    for (int dy = -1; dy <= 1; ++dy)
      for (int dx = -1; dx <= 1; ++dx) {
        int y = yb + dy, x = xb + dx;
        if ((unsigned)y < 64u && (unsigned)x < 64u) s += s2[y * 64 + x];
      }
    rnrm[p] = rsqrtf(s + 1152.0f * 1.0e-4f);
  }
}

// ---------------------------------------------------------------------------
// MFMA bf16 GEMM: Out[m,n] = sum_k A[m*lda+k]*B[n*ldb+k]  (K-major operands)
// Block tile 256x256, 256 threads = 4 waves (2m x 2n), wave tile 128x128 as
// 4x4 subtiles of 32x32x16 MFMA. acc[4][4] = 256 AGPRs -> 1 wave/SIMD
// (launch_bounds(256,1); unified 512-reg file). Per k-step: 8 ds_read_b128
// feed 16 MFMAs (0.5 KB/MFMA — LDS wall ~= MFMA wall, balanced).
// BK=64 (4 k-steps of 16), ring-2 LDS (128 KB), software-pipelined frag reads,
// ONE barrier pair per tile, staging of t+2 hidden under last MFMA cluster,
// counted vmcnt(16) (never 0 mid-loop). blockIdx.z = K-split.
__global__ __launch_bounds__(256, 1) void k_mfma_gemm(const ushort* __restrict__ A,
                                                      const ushort* __restrict__ B,
                                                      float* __restrict__ Out,
                                                      int Kdim, int lda, int ldb, int ldo,
                                                      long osplit) {
  __shared__ ushort As[2][256 * 64];
  __shared__ ushort Bs[2][256 * 64];
  const int tid = threadIdx.x;
  const int wave = tid >> 6, lane = tid & 63;
  const int l32 = lane & 31, khalf = lane >> 5;
  const int m0 = blockIdx.y * 256, n0 = blockIdx.x * 256;
  const int wm = (wave >> 1) * 128, wn = (wave & 1) * 128;
  const int srow = lane >> 3;                    // 0..7
  const int gperm = ((lane & 7) ^ srow) * 8;     // XOR source-swizzle (verified)

  const int koff = blockIdx.z * Kdim;
  A += koff; B += koff;
  Out += (size_t)blockIdx.z * osplit;

  // staging: per tile, A = 8 instrs/wave (8 rows each), B = 8 instrs/wave.
  // instr q of wave w covers rows q*32 + w*8 + (0..7); LDS dest linear.
  const ushort* Ag = A + (size_t)(m0 + wave * 8 + srow) * lda + gperm;
  const ushort* Bg = B + (size_t)(n0 + wave * 8 + srow) * ldb + gperm;
  ushort* AsW = &As[0][0] + (wave * 8) * 64;
  ushort* BsW = &Bs[0][0] + (wave * 8) * 64;

#define STG_A(sl, tt, q) gl2lds16(Ag + (size_t)((q) * 32) * lda + ((tt) << 6), \
                                  AsW + (sl) * 16384 + (q) * 2048)
#define STG_B(sl, tt, q) gl2lds16(Bg + (size_t)((q) * 32) * ldb + ((tt) << 6), \
                                  BsW + (sl) * 16384 + (q) * 2048)
#define STG_TILE(sl, tt) do { \
  _Pragma("unroll") for (int q = 0; q < 8; ++q) { STG_A(sl, tt, q); STG_B(sl, tt, q); } \
} while (0)

  f16a acc[4][4];
#pragma unroll
  for (int u = 0; u < 4; ++u)
#pragma unroll
    for (int v = 0; v < 4; ++v)
#pragma unroll
      for (int r = 0; r < 16; ++r) acc[u][v][r] = 0.f;

  const int NT = Kdim >> 6;

  // prologue: stage tiles 0 and 1
  STG_TILE(0, 0);
  if (NT > 1) {
    STG_TILE(1, 1);
    asm volatile("s_waitcnt vmcnt(16)" ::: "memory");  // tile 0 landed, tile 1 in flight
  } else {
    asm volatile("s_waitcnt vmcnt(0)" ::: "memory");
  }
  __builtin_amdgcn_s_barrier();

  for (int t = 0; t < NT; ++t) {
    const int sl = t & 1;
    const ushort* Ar = &As[sl][0];
    const ushort* Br = &Bs[sl][0];
    short8 af[2][4], bf[2][4];

#define FRAG_READS(sidx) do { \
  _Pragma("unroll") for (int u = 0; u < 4; ++u) { \
    int am = wm + u * 32 + l32; \
    int ga = (((sidx) * 2 + khalf) ^ (am & 7)) * 8; \
    af[(sidx) & 1][u] = *reinterpret_cast<const short8*>(&Ar[am * 64 + ga]); } \
  _Pragma("unroll") for (int v = 0; v < 4; ++v) { \
    int bn = wn + v * 32 + l32; \
    int gb = (((sidx) * 2 + khalf) ^ (bn & 7)) * 8; \
    bf[(sidx) & 1][v] = *reinterpret_cast<const short8*>(&Br[bn * 64 + gb]); } \
} while (0)

    FRAG_READS(0);
#pragma unroll
    for (int s = 0; s < 4; ++s) {
      if (s == 1) FRAG_READS(2);
      if (s == 2) FRAG_READS(3);
      if (s == 0) FRAG_READS(1);
      if (s == 3) {
        // all slot-sl reads of this wave are complete after this wait
        asm volatile("s_waitcnt lgkmcnt(0)" ::: "memory");
        __builtin_amdgcn_sched_barrier(0);
        __builtin_amdgcn_s_barrier();              // all waves done reading slot sl
        __builtin_amdgcn_sched_barrier(0);
        if (t + 2 < NT) STG_TILE(sl, t + 2);       // race-free: slot sl fully consumed
        __builtin_amdgcn_s_setprio(1);
      }
#pragma unroll
      for (int u = 0; u < 4; ++u)
#pragma unroll
        for (int v = 0; v < 4; ++v)
          acc[u][v] = __builtin_amdgcn_mfma_f32_32x32x16_bf16(af[s & 1][u], bf[s & 1][v],
                                                              acc[u][v], 0, 0, 0);
      if (s == 3) __builtin_amdgcn_s_setprio(0);
    }
    if (t + 1 < NT) {
      if (t + 2 < NT) asm volatile("s_waitcnt vmcnt(16)" ::: "memory"); // t+1 landed, t+2 in flight
      else            asm volatile("s_waitcnt vmcnt(0)" ::: "memory");  // tail drain
      __builtin_amdgcn_s_barrier();
    }
#undef FRAG_READS
  }

#pragma unroll
  for (int u = 0; u < 4; ++u)
#pragma unroll
    for (int v = 0; v < 4; ++v)
#pragma unroll
      for (int r = 0; r < 16; ++r) {
        int row = (r & 3) + 8 * (r >> 2) + 4 * khalf;
        Out[(size_t)(m0 + wm + u * 32 + row) * ldo + (n0 + wn + v * 32 + l32)] = acc[u][v][r];
      }
#undef STG_A
#undef STG_B
#undef STG_TILE
}

// ---------------------------------------------------------------------------
// S0[p,q] = (sum of 9 diag-shifted D taps) * rnrm[p]
__global__ __launch_bounds__(256) void k_s0(const float* __restrict__ D,
                                            const float* __restrict__ rnrm,
                                            float* __restrict__ S0) {
  int p = blockIdx.x;
  int yb = p >> 6, xb = p & 63;
  float rp = rnrm[p];
  int t = threadIdx.x;
#pragma unroll
  for (int it = 0; it < 4; ++it) {
    int q = (it * 256 + t) << 2;
    int qy = q >> 6, qx = q & 63;
    f4a16 acc = (f4a16){0.f, 0.f, 0.f, 0.f};
#pragma unroll
    for (int dy = -1; dy <= 1; ++dy) {
      if ((unsigned)(yb + dy) >= 64u) continue;
      if ((unsigned)(qy + dy) >= 64u) continue;
#pragma unroll
      for (int dx = -1; dx <= 1; ++dx) {
        if ((unsigned)(xb + dx) >= 64u) continue;
        int delta = dy * 64 + dx;
        const float* base = D + (size_t)(p + delta) * 4096;
        f4u v;
        if (dx == -1 && qx == 0) {
          f4u r = *(const f4u*)(base + q + delta + 1);  // avoid negative addr
          v = (f4u){0.f, r.x, r.y, r.z};
        } else {
          v = *(const f4u*)(base + q + delta);
          if (dx == 1 && qx == 60) v.w = 0.f;
        }
        acc += v;
      }
    }
    acc *= rp;
    *(f4a16*)(S0 + ((size_t)p << 12) + q) = acc;
  }
}

// fuse1: F1[i,j] = sum_d S0[i+d, j+d], written permuted: Yp[pi(i)][b]=F1[i][pi(b)]
__global__ __launch_bounds__(256) void k_fuse1(const float* __restrict__ S0,
                                               float* __restrict__ Yp) {
  __shared__ float row[4160];
  int i = blockIdx.x;
  int t = threadIdx.x;
  const float* r0 = S0 + (size_t)(i - 1) * 4096;
  const float* r1 = S0 + (size_t)i * 4096;
  const float* r2 = S0 + (size_t)(i + 1) * 4096;
  bool up = (i > 0), dn = (i < 4095);
#pragma unroll
  for (int jj = 0; jj < 4; ++jj) {
    int j = (jj * 256 + t) << 2;
    f4u s = *(const f4u*)(r1 + j);
    if (up) {
      f4u a;
      if (j == 0) { f4u r = *(const f4u*)r0; a = (f4u){0.f, r.x, r.y, r.z}; }
      else a = *(const f4u*)(r0 + j - 1);
      s += a;
    }
    if (dn) {
      f4u d = *(const f4u*)(r2 + j + 1);
      if (j == 4092) d.w = 0.f;
      s += d;
    }
    int base = j + (j >> 6);
    row[base + 0] = s.x; row[base + 1] = s.y; row[base + 2] = s.z; row[base + 3] = s.w;
  }
  __syncthreads();
  int a = ((i & 63) << 6) | (i >> 6);
  float* orow = Yp + ((size_t)a << 12);
#pragma unroll
  for (int bb = 0; bb < 4; ++bb) {
    int b4 = (bb * 256 + t) << 2;
    f4a16 o;
#pragma unroll
    for (int k = 0; k < 4; ++k) {
      int jT = (((b4 + k) & 63) << 6) | ((b4 + k) >> 6);
      o[k] = row[jT + (jT >> 6)];
    }
    *(f4a16*)(orow + b4) = o;
  }
}

// softmax partials over u of logits x = 10 * mmp[u] * diag3(Yp)[u,v]
__global__ __launch_bounds__(256) void k_smax_part(const float* __restrict__ Yp,
                                                   const float* __restrict__ mmp,
                                                   float* __restrict__ pm,
                                                   float* __restrict__ ps) {
  int v = (blockIdx.x * 256 + threadIdx.x) << 2;
  int chunk = blockIdx.y;
  f4a16 m = (f4a16){-1e30f, -1e30f, -1e30f, -1e30f};
  f4a16 s = (f4a16){0.f, 0.f, 0.f, 0.f};
  int u0 = chunk * (4096 / NCHUNK);
  for (int u = u0; u < u0 + (4096 / NCHUNK); ++u) {
    const float* row = Yp + ((size_t)u << 12);
    f4u tv = *(const f4u*)(row + v);
    if (u > 0) {
      f4u a;
      if (v == 0) { f4u r = *(const f4u*)(row - 4096); a = (f4u){0.f, r.x, r.y, r.z}; }
      else a = *(const f4u*)(row - 4096 + v - 1);
      tv += a;
    }
    if (u < 4095) {
      f4u d = *(const f4u*)(row + 4096 + v + 1);
      if (v == 4092) d.w = 0.f;
      tv += d;
    }
    float g = 10.0f * mmp[u];
    f4u x = tv * g;
#pragma unroll
    for (int l = 0; l < 4; ++l) {
      float xl = x[l];
      if (xl > m[l]) { s[l] = s[l] * __expf(m[l] - xl) + 1.0f; m[l] = xl; }
      else           { s[l] += __expf(xl - m[l]); }
    }
  }
  *(f4a16*)(pm + chunk * NP + v) = m;
  *(f4a16*)(ps + chunk * NP + v) = s;
}

// ---------------------------------------------------------------------------
// epilogue (flattened 6144-block grid): attnT tiles w/ local softmax reduction,
// and VtT transpose blocks.
__global__ __launch_bounds__(256) void k_epilogue(const float* __restrict__ Yp,
                                                  const float* __restrict__ pm,
                                                  const float* __restrict__ ps,
                                                  const float* __restrict__ mmp,
                                                  ushort* __restrict__ AT,
                                                  const float* __restrict__ bimg,
                                                  ushort* __restrict__ VtT) {
  __shared__ float T[64][65];
  __shared__ float pmS[4][64];
  __shared__ float psS[4][64];
  __shared__ float mS[64];
  __shared__ float rsS[64];
  int gx = blockIdx.x;
  int t = threadIdx.x;
  if (gx < 4096) {
    int a0 = (gx & 63) * 64, b0 = (gx >> 6) * 64;
    int j = t & 63, grp = t >> 6;
    float m = -1e30f, s = 0.f;
    for (int ch = grp * 16; ch < grp * 16 + 16; ++ch) {
      float m2 = pm[ch * NP + b0 + j], s2 = ps[ch * NP + b0 + j];
      if (m2 > m) { s = s * __expf(m - m2) + s2; m = m2; }
      else        { s += s2 * __expf(m2 - m); }
    }
    pmS[grp][j] = m; psS[grp][j] = s;
    __syncthreads();
    if (grp == 0) {
      for (int g2 = 1; g2 < 4; ++g2) {
        float m2 = pmS[g2][j], s2 = psS[g2][j];
        if (m2 > m) { s = s * __expf(m - m2) + s2; m = m2; }
        else        { s += s2 * __expf(m2 - m); }
      }
      mS[j] = m; rsS[j] = 1.0f / s;
    }
    __syncthreads();
    int i = t >> 4, j4 = (t & 15) << 2;
    f4a16 mc = *(const f4a16*)&mS[j4];
    f4a16 rs = *(const f4a16*)&rsS[j4];
#pragma unroll
    for (int r = 0; r < 4; ++r) {
      int al = r * 16 + i;
      int a = a0 + al;
      const float* row = Yp + ((size_t)a << 12);
      int b = b0 + j4;
      f4u y = *(const f4u*)(row + b);
      if (a > 0) {
        f4u u_;
        if (b == 0) { f4u rr = *(const f4u*)(row - 4096); u_ = (f4u){0.f, rr.x, rr.y, rr.z}; }
        else u_ = *(const f4u*)(row - 4096 + b - 1);
        y += u_;
      }
      if (a < 4095) {
        f4u d = *(const f4u*)(row + 4096 + b + 1);
        if (b == 4092) d.w = 0.f;
        y += d;
      }
      float g = mmp[a];
      f4u x = y * (10.0f * g);
#pragma unroll
      for (int l = 0; l < 4; ++l)
        T[al][j4 + l] = g * __expf(x[l] - mc[l]) * rs[l];
    }
    __syncthreads();
    int by0 = b0 >> 6;
    int cgrp = (t & 7) * 8;
#pragma unroll
    for (int pass = 0; pass < 2; ++pass) {
      int bl = pass * 32 + (t >> 3);
      int q = bl * 64 + by0;                   // pi(b0 + bl)
      uint4 w;
      w.x = (unsigned)f2bf(T[cgrp + 0][bl]) | ((unsigned)f2bf(T[cgrp + 1][bl]) << 16);
      w.y = (unsigned)f2bf(T[cgrp + 2][bl]) | ((unsigned)f2bf(T[cgrp + 3][bl]) << 16);
      w.z = (unsigned)f2bf(T[cgrp + 4][bl]) | ((unsigned)f2bf(T[cgrp + 5][bl]) << 16);
      w.w = (unsigned)f2bf(T[cgrp + 6][bl]) | ((unsigned)f2bf(T[cgrp + 7][bl]) << 16);
      *(uint4*)(AT + ((size_t)q << 12) + a0 + cgrp) = w;
    }
  } else {
    int k2 = gx - 4096;
    int c = k2 >> 4, dy = (k2 >> 2) & 3, dx = k2 & 3;
    int px = t & 63;
#pragma unroll
    for (int r = 0; r < 16; ++r) {
      int py = r * 4 + (t >> 6);
      int sy = 2 * py + dy - 1, sx = 2 * px + dx - 1;
      float v = 0.f;
      if ((unsigned)sy < (unsigned)HF && (unsigned)sx < (unsigned)WF)
        v = bimg[c * 16384 + sy * 128 + sx];
      T[py][px] = v;
    }
    __syncthreads();
    ushort* orow = VtT + (size_t)k2 * 4096;
#pragma unroll
    for (int r = 0; r < 16; ++r) {
      int a = r * 256 + t;
      orow[a] = f2bf(T[a & 63][a >> 6]);
    }
  }
}

// scatter M[(c,dy,dx), q] -> out (transposed conv, lhs_dilation=2), /4
// reads BOTH split-K halves (Ma + Mb)
__global__ __launch_bounds__(256) void k_scatter(const float* __restrict__ Ma,
                                                 const float* __restrict__ Mb,
                                                 float* __restrict__ out) {
  int idx = blockIdx.x * 256 + threadIdx.x;
  int ox = idx & 127, oy = (idx >> 7) & 127, c = idx >> 14;
  int qy[2], dyv[2], qx[2], dxv[2];
  if (oy & 1) { qy[0] = (oy - 1) >> 1; dyv[0] = 2; qy[1] = (oy + 1) >> 1; dyv[1] = 0; }
  else        { qy[0] = (oy >> 1) - 1; dyv[0] = 3; qy[1] = oy >> 1;       dyv[1] = 1; }
  if (ox & 1) { qx[0] = (ox - 1) >> 1; dxv[0] = 2; qx[1] = (ox + 1) >> 1; dxv[1] = 0; }
  else        { qx[0] = (ox >> 1) - 1; dxv[0] = 3; qx[1] = ox >> 1;       dxv[1] = 1; }
  float s = 0.f;
#pragma unroll
  for (int i = 0; i < 2; ++i) {
    if ((unsigned)qy[i] >= 64u) continue;
#pragma unroll
    for (int j = 0; j < 2; ++j) {
      if ((unsigned)qx[j] >= 64u) continue;
      int k = c * 16 + dyv[i] * 4 + dxv[j];
      size_t off = (size_t)k * NP + qy[i] * 64 + qx[j];
      s += Ma[off] + Mb[off];
    }
  }
  out[idx] = 0.25f * s;
}

// ---------------------------------------------------------------------------
extern "C" void kernel_launch(void* const* d_in, const int* in_sizes, int n_in,
                              void* d_out, int out_size, void* d_ws, size_t ws_size,
                              hipStream_t stream) {
  const float* f_all = (const float*)d_in[0];
  const float* b_all = (const float*)d_in[1];
  const float* m_all = (const float*)d_in[2];
  float* out = (float*)d_out;

  float* ws = (float*)d_ws;
  float* bufD = ws;                          // 64MB: D -> Yp -> {M0, M1}
  float* bufS = ws + 16777216;               // 64MB: {fcat,bcat} -> S0 -> {AT, VtT}
  ushort* fcat = (ushort*)bufS;
  ushort* bcat = (ushort*)(bufS + 786432);
  float* S0  = bufS;
  float* Yp  = bufD;
  ushort* AT  = (ushort*)bufS;               // 32MB
  ushort* VtT = (ushort*)(bufS + 8388608);   // 16MB
  float* M0 = bufD;                          // 32MB (clobbers Yp)
  float* M1 = bufD + 8388608;                // 32MB
  float* smalls = ws + 2 * 16777216;
  float* s2    = smalls;
  float* rnrm  = s2 + 4096;
  float* mmp   = rnrm + 4096;
  float* pm    = mmp + 4096;
  float* ps    = pm + NCHUNK * NP;

  const size_t zsF = (size_t)CDIM * HF * WF;
  const size_t zsM = (size_t)HF * WF;

  for (int it = 0; it < 2; ++it) {
    const float* f = f_all + it * zsF;
    const float* b = b_all + it * zsF;
    const float* mk = m_all + it * zsM;
    float* o = out + it * zsF;

    k_prep<<<2048, 256, 0, stream>>>(f, b, fcat, bcat, s2);
    k_mmpnorm<<<32, 256, 0, stream>>>(mk, s2, mmp, rnrm);
    // D[p,q] (fp32-accurate via split-bf16, K=384): 256x256 tiles, 256 blocks
    k_mfma_gemm<<<dim3(16, 16, 1), 256, 0, stream>>>(bcat, fcat, bufD, 384, 384, 384, NP, 0);
    k_s0<<<4096, 256, 0, stream>>>(bufD, rnrm, S0);
    k_fuse1<<<4096, 256, 0, stream>>>(S0, Yp);
    k_smax_part<<<dim3(4, NCHUNK), 256, 0, stream>>>(Yp, mmp, pm, ps);
    k_epilogue<<<6144, 256, 0, stream>>>(Yp, pm, ps, mmp, AT, b, VtT);
    // M[k2,q] = sum_a VtT[k2,a] * AT[q,a]  (K=4096, split-K=2 -> 256 blocks)
    k_mfma_gemm<<<dim3(16, 8, 2), 256, 0, stream>>>(VtT, AT, M0, 2048, NP, NP, NP,
                                                    (long)2048 * 4096);
    k_scatter<<<8192, 256, 0, stream>>>(M0, M1, o);
  }
}

// Round 4
// 604.529 us; speedup vs baseline: 1.0897x; 1.0897x over previous
//
#include <hip/hip_runtime.h>
#include <math.h>

// KSIZE=3, STRIDE=1, RATE=2, FUSE_K=3, SCALE=10
#define CDIM 128
#define HF   128
#define WF   128
#define NP   4096   // 64*64 downsampled positions
#define NCHUNK 64   // softmax u-chunks (64 rows each)

typedef __attribute__((ext_vector_type(8))) short short8;
typedef __attribute__((ext_vector_type(16))) float f16a;
typedef float __attribute__((ext_vector_type(4), aligned(16))) f4a16;
typedef float __attribute__((ext_vector_type(4), aligned(4)))  f4u;

__device__ inline ushort f2bf(float x) {
  union { float f; unsigned u; } v; v.f = x;
  unsigned r = v.u + 0x7fff + ((v.u >> 16) & 1);
  return (ushort)(r >> 16);
}
__device__ inline float bf2f(ushort h) {
  union { unsigned u; float f; } v; v.u = ((unsigned)h) << 16; return v.f;
}

__device__ inline void gl2lds16(const ushort* g, ushort* l) {
  __builtin_amdgcn_global_load_lds((const __attribute__((address_space(1))) void*)g,
                                   (__attribute__((address_space(3))) void*)l, 16, 0, 0);
}

// ---------------------------------------------------------------------------
// prep: downsample + split fp32 -> (hi,lo) bf16 K-major cat operands, AND
// s2[p] = sum_c b_ds[c,p]^2
__global__ __launch_bounds__(256) void k_prep(const float* __restrict__ f,
                                              const float* __restrict__ b,
                                              ushort* __restrict__ fcat,
                                              ushort* __restrict__ bcat,
                                              float* __restrict__ s2) {
  int idx = blockIdx.x * 256 + threadIdx.x;   // 524288
  int c = idx & 127, pos = idx >> 7;
  int x = pos & 63, y = pos >> 6;
  int src = c * 16384 + y * 256 + x * 2;
  float fv = f[src], bv = b[src];
  ushort fh = f2bf(fv); ushort fl = f2bf(fv - bf2f(fh));
  ushort bh = f2bf(bv); ushort bl = f2bf(bv - bf2f(bh));
  size_t base = (size_t)pos * 384;
  fcat[base + c] = fh; fcat[base + 128 + c] = fl; fcat[base + 256 + c] = fh;
  bcat[base + c] = bh; bcat[base + 128 + c] = bh; bcat[base + 256 + c] = bl;
  float sq = bv * bv;
#pragma unroll
  for (int off = 32; off; off >>= 1) sq += __shfl_down(sq, off);
  __shared__ float wsum[4];
  if ((threadIdx.x & 63) == 0) wsum[threadIdx.x >> 6] = sq;
  __syncthreads();
  if (threadIdx.x == 0) s2[blockIdx.x * 2]     = wsum[0] + wsum[1];
  if (threadIdx.x == 1) s2[blockIdx.x * 2 + 1] = wsum[2] + wsum[3];
}

// merged: blocks 0..15 -> mmp[a] (mask gate at p=pi(a)); 16..31 -> rnrm[p]
__global__ __launch_bounds__(256) void k_mmpnorm(const float* __restrict__ mask,
                                                 const float* __restrict__ s2,
                                                 float* __restrict__ mmp,
                                                 float* __restrict__ rnrm) {
  int bx = blockIdx.x, t = threadIdx.x;
  if (bx < 16) {
    int a = bx * 256 + t;
    int yb = a & 63, xb = a >> 6;               // p = pi(a)
    float s = 0.f;
    for (int dy = -1; dy <= 1; ++dy)
      for (int dx = -1; dx <= 1; ++dx) {
        int y = yb + dy, x = xb + dx;
        if ((unsigned)y < 64u && (unsigned)x < 64u)
          s += mask[y * 256 + x * 2];
      }
    mmp[a] = (s == 0.0f) ? 1.0f : 0.0f;
  } else {
    int p = (bx - 16) * 256 + t;
    int xb = p & 63, yb = p >> 6;
    float s = 0.f;
    for (int dy = -1; dy <= 1; ++dy)
      for (int dx = -1; dx <= 1; ++dx) {
        int y = yb + dy, x = xb + dx;
        if ((unsigned)y < 64u && (unsigned)x < 64u) s += s2[y * 64 + x];
      }
    rnrm[p] = rsqrtf(s + 1152.0f * 1.0e-4f);
  }
}

// ---------------------------------------------------------------------------
// MFMA bf16 GEMM: Out[m,n] = sum_k A[m*lda+k]*B[n*ldb+k]  (K-major operands)
// R2-proven structure (71.6us GEMM2): block 256x256, 512 threads = 8 waves
// (2m x 4n), wave tile 128x64 as 4x2 subtiles of 32x32x16 MFMA, BK=64,
// ring-2 LDS (128 KB), software-pipelined frag reads, ONE barrier pair per
// tile, staging of t+2 under last MFMA cluster, counted vmcnt(8).
// NEW: bijective XCD swizzle of the (x,y,z) grid (grid size % 8 == 0) so each
// XCD gets contiguous swz chunks -> shared A-panels become L2 hits.
__global__ __launch_bounds__(512) void k_mfma_gemm(const ushort* __restrict__ A,
                                                   const ushort* __restrict__ B,
                                                   float* __restrict__ Out,
                                                   int Kdim, int lda, int ldb, int ldo,
                                                   long osplit) {
  __shared__ ushort As[2][256 * 64];
  __shared__ ushort Bs[2][256 * 64];
  const int tid = threadIdx.x;
  const int wave = tid >> 6, lane = tid & 63;
  const int l32 = lane & 31, khalf = lane >> 5;

  // bijective XCD swizzle (total blocks divisible by 8)
  unsigned nbx = gridDim.x, nby = gridDim.y;
  unsigned lid = blockIdx.x + nbx * (blockIdx.y + nby * blockIdx.z);
  unsigned cpx = (nbx * nby * gridDim.z) >> 3;
  unsigned swz = (lid & 7) * cpx + (lid >> 3);
  unsigned bx = swz % nbx;
  unsigned tmp = swz / nbx;
  unsigned by = tmp % nby, bz = tmp / nby;

  const int m0 = by * 256, n0 = bx * 256;
  const int wm = (wave >> 2) * 128, wn = (wave & 3) * 64;
  const int srow = lane >> 3;                    // 0..7
  const int gperm = ((lane & 7) ^ srow) * 8;     // XOR source-swizzle (verified)

  const int koff = bz * Kdim;
  A += koff; B += koff;
  Out += (size_t)bz * osplit;

  // staging: per tile, A = 4 instrs (64 rows each), B = 4 instrs.
  // wave stages rows q*64 + wave*8 + (0..7); LDS dest linear per wave stripe.
  const ushort* Ag = A + (size_t)(m0 + wave * 8 + srow) * lda + gperm;
  const ushort* Bg = B + (size_t)(n0 + wave * 8 + srow) * ldb + gperm;
  ushort* AsW = &As[0][0] + (wave * 8) * 64;
  ushort* BsW = &Bs[0][0] + (wave * 8) * 64;

#define STG_A(sl, tt, q) gl2lds16(Ag + (size_t)((q) * 64) * lda + ((tt) << 6), \
                                  AsW + (sl) * 16384 + (q) * 4096)
#define STG_B(sl, tt, q) gl2lds16(Bg + (size_t)((q) * 64) * ldb + ((tt) << 6), \
                                  BsW + (sl) * 16384 + (q) * 4096)

  f16a acc[4][2];
#pragma unroll
  for (int u = 0; u < 4; ++u)
#pragma unroll
    for (int v = 0; v < 2; ++v)
#pragma unroll
      for (int r = 0; r < 16; ++r) acc[u][v][r] = 0.f;

  const int NT = Kdim >> 6;

  // prologue: stage tiles 0 and 1
#pragma unroll
  for (int q = 0; q < 4; ++q) { STG_A(0, 0, q); STG_B(0, 0, q); }
  if (NT > 1) {
#pragma unroll
    for (int q = 0; q < 4; ++q) { STG_A(1, 1, q); STG_B(1, 1, q); }
    asm volatile("s_waitcnt vmcnt(8)" ::: "memory");   // tile 0 landed
  } else {
    asm volatile("s_waitcnt vmcnt(0)" ::: "memory");
  }
  __builtin_amdgcn_s_barrier();

  for (int t = 0; t < NT; ++t) {
    const int sl = t & 1;
    const ushort* Ar = &As[sl][0];
    const ushort* Br = &Bs[sl][0];
    short8 af[2][4], bf[2][2];

#define FRAG_READS(sidx) do { \
  _Pragma("unroll") for (int u = 0; u < 4; ++u) { \
    int am = wm + u * 32 + l32; \
    int ga = (((sidx) * 2 + khalf) ^ (am & 7)) * 8; \
    af[(sidx) & 1][u] = *reinterpret_cast<const short8*>(&Ar[am * 64 + ga]); } \
  _Pragma("unroll") for (int v = 0; v < 2; ++v) { \
    int bn = wn + v * 32 + l32; \
    int gb = (((sidx) * 2 + khalf) ^ (bn & 7)) * 8; \
    bf[(sidx) & 1][v] = *reinterpret_cast<const short8*>(&Br[bn * 64 + gb]); } \
} while (0)

    FRAG_READS(0);
#pragma unroll
    for (int s = 0; s < 4; ++s) {
      if (s == 1) FRAG_READS(2);
      if (s == 2) FRAG_READS(3);
      if (s == 0) FRAG_READS(1);
      if (s == 3) {
        // all slot-sl reads of this wave are complete after this wait
        asm volatile("s_waitcnt lgkmcnt(0)" ::: "memory");
        __builtin_amdgcn_sched_barrier(0);
        __builtin_amdgcn_s_barrier();              // all waves done reading slot sl
        __builtin_amdgcn_sched_barrier(0);
        if (t + 2 < NT) {                          // stage tile t+2 into slot sl
#pragma unroll
          for (int q = 0; q < 4; ++q) { STG_A(sl, t + 2, q); STG_B(sl, t + 2, q); }
        }
        __builtin_amdgcn_s_setprio(1);
      }
#pragma unroll
      for (int u = 0; u < 4; ++u)
#pragma unroll
        for (int v = 0; v < 2; ++v)
          acc[u][v] = __builtin_amdgcn_mfma_f32_32x32x16_bf16(af[s & 1][u], bf[s & 1][v],
                                                              acc[u][v], 0, 0, 0);
      if (s == 3) __builtin_amdgcn_s_setprio(0);
    }
    if (t + 1 < NT) {
      if (t + 2 < NT) asm volatile("s_waitcnt vmcnt(8)" ::: "memory");  // t+1 landed, t+2 in flight
      else            asm volatile("s_waitcnt vmcnt(0)" ::: "memory");  // tail drain
      __builtin_amdgcn_s_barrier();
    }
#undef FRAG_READS
  }

#pragma unroll
  for (int u = 0; u < 4; ++u)
#pragma unroll
    for (int v = 0; v < 2; ++v)
#pragma unroll
      for (int r = 0; r < 16; ++r) {
        int row = (r & 3) + 8 * (r >> 2) + 4 * khalf;
        Out[(size_t)(m0 + wm + u * 32 + row) * ldo + (n0 + wn + v * 32 + l32)] = acc[u][v][r];
      }
#undef STG_A
#undef STG_B
}

// ---------------------------------------------------------------------------
// S0[p,q] = (sum of 9 diag-shifted D taps) * rnrm[p]
// XCD-swizzled: each XCD owns a contiguous 512-p chunk so the 6/9 rows shared
// by neighboring p are L2 hits instead of cross-XCD refetches.
__global__ __launch_bounds__(256) void k_s0(const float* __restrict__ D,
                                            const float* __restrict__ rnrm,
                                            float* __restrict__ S0) {
  int p = ((blockIdx.x & 7) << 9) | (blockIdx.x >> 3);   // bijective, 4096 % 8 == 0
  int yb = p >> 6, xb = p & 63;
  float rp = rnrm[p];
  int t = threadIdx.x;
#pragma unroll
  for (int it = 0; it < 4; ++it) {
    int q = (it * 256 + t) << 2;
    int qy = q >> 6, qx = q & 63;
    f4a16 acc = (f4a16){0.f, 0.f, 0.f, 0.f};
#pragma unroll
    for (int dy = -1; dy <= 1; ++dy) {
      if ((unsigned)(yb + dy) >= 64u) continue;
      if ((unsigned)(qy + dy) >= 64u) continue;
#pragma unroll
      for (int dx = -1; dx <= 1; ++dx) {
        if ((unsigned)(xb + dx) >= 64u) continue;
        int delta = dy * 64 + dx;
        const float* base = D + (size_t)(p + delta) * 4096;
        f4u v;
        if (dx == -1 && qx == 0) {
          f4u r = *(const f4u*)(base + q + delta + 1);  // avoid negative addr
          v = (f4u){0.f, r.x, r.y, r.z};
        } else {
          v = *(const f4u*)(base + q + delta);
          if (dx == 1 && qx == 60) v.w = 0.f;
        }
        acc += v;
      }
    }
    acc *= rp;
    *(f4a16*)(S0 + ((size_t)p << 12) + q) = acc;
  }
}

// fuse1: F1[i,j] = sum_d S0[i+d, j+d], written permuted: Yp[pi(i)][b]=F1[i][pi(b)]
// XCD-swizzled (consecutive i share 2 of 3 input rows).
__global__ __launch_bounds__(256) void k_fuse1(const float* __restrict__ S0,
                                               float* __restrict__ Yp) {
  __shared__ float row[4160];
  int i = ((blockIdx.x & 7) << 9) | (blockIdx.x >> 3);   // bijective, 4096 % 8 == 0
  int t = threadIdx.x;
  const float* r0 = S0 + (size_t)(i - 1) * 4096;
  const float* r1 = S0 + (size_t)i * 4096;
  const float* r2 = S0 + (size_t)(i + 1) * 4096;
  bool up = (i > 0), dn = (i < 4095);
#pragma unroll
  for (int jj = 0; jj < 4; ++jj) {
    int j = (jj * 256 + t) << 2;
    f4u s = *(const f4u*)(r1 + j);
    if (up) {
      f4u a;
      if (j == 0) { f4u r = *(const f4u*)r0; a = (f4u){0.f, r.x, r.y, r.z}; }
      else a = *(const f4u*)(r0 + j - 1);
      s += a;
    }
    if (dn) {
      f4u d = *(const f4u*)(r2 + j + 1);
      if (j == 4092) d.w = 0.f;
      s += d;
    }
    int base = j + (j >> 6);
    row[base + 0] = s.x; row[base + 1] = s.y; row[base + 2] = s.z; row[base + 3] = s.w;
  }
  __syncthreads();
  int a = ((i & 63) << 6) | (i >> 6);
  float* orow = Yp + ((size_t)a << 12);
#pragma unroll
  for (int bb = 0; bb < 4; ++bb) {
    int b4 = (bb * 256 + t) << 2;
    f4a16 o;
#pragma unroll
    for (int k = 0; k < 4; ++k) {
      int jT = (((b4 + k) & 63) << 6) | ((b4 + k) >> 6);
      o[k] = row[jT + (jT >> 6)];
    }
    *(f4a16*)(orow + b4) = o;
  }
}

// softmax partials over u of logits x = 10 * mmp[u] * diag3(Yp)[u,v]
__global__ __launch_bounds__(256) void k_smax_part(const float* __restrict__ Yp,
                                                   const float* __restrict__ mmp,
                                                   float* __restrict__ pm,
                                                   float* __restrict__ ps) {
  int v = (blockIdx.x * 256 + threadIdx.x) << 2;
  int chunk = blockIdx.y;
  f4a16 m = (f4a16){-1e30f, -1e30f, -1e30f, -1e30f};
  f4a16 s = (f4a16){0.f, 0.f, 0.f, 0.f};
  int u0 = chunk * (4096 / NCHUNK);
  for (int u = u0; u < u0 + (4096 / NCHUNK); ++u) {
    const float* row = Yp + ((size_t)u << 12);
    f4u tv = *(const f4u*)(row + v);
    if (u > 0) {
      f4u a;
      if (v == 0) { f4u r = *(const f4u*)(row - 4096); a = (f4u){0.f, r.x, r.y, r.z}; }
      else a = *(const f4u*)(row - 4096 + v - 1);
      tv += a;
    }
    if (u < 4095) {
      f4u d = *(const f4u*)(row + 4096 + v + 1);
      if (v == 4092) d.w = 0.f;
      tv += d;
    }
    float g = 10.0f * mmp[u];
    f4u x = tv * g;
#pragma unroll
    for (int l = 0; l < 4; ++l) {
      float xl = x[l];
      if (xl > m[l]) { s[l] = s[l] * __expf(m[l] - xl) + 1.0f; m[l] = xl; }
      else           { s[l] += __expf(xl - m[l]); }
    }
  }
  *(f4a16*)(pm + chunk * NP + v) = m;
  *(f4a16*)(ps + chunk * NP + v) = s;
}

// ---------------------------------------------------------------------------
// epilogue (flattened 6144-block grid): attnT tiles w/ local softmax reduction,
// and VtT transpose blocks.
__global__ __launch_bounds__(256) void k_epilogue(const float* __restrict__ Yp,
                                                  const float* __restrict__ pm,
                                                  const float* __restrict__ ps,
                                                  const float* __restrict__ mmp,
                                                  ushort* __restrict__ AT,
                                                  const float* __restrict__ bimg,
                                                  ushort* __restrict__ VtT) {
  __shared__ float T[64][65];
  __shared__ float pmS[4][64];
  __shared__ float psS[4][64];
  __shared__ float mS[64];
  __shared__ float rsS[64];
  int gx = blockIdx.x;
  int t = threadIdx.x;
  if (gx < 4096) {
    int a0 = (gx & 63) * 64, b0 = (gx >> 6) * 64;
    int j = t & 63, grp = t >> 6;
    float m = -1e30f, s = 0.f;
    for (int ch = grp * 16; ch < grp * 16 + 16; ++ch) {
      float m2 = pm[ch * NP + b0 + j], s2 = ps[ch * NP + b0 + j];
      if (m2 > m) { s = s * __expf(m - m2) + s2; m = m2; }
      else        { s += s2 * __expf(m2 - m); }
    }
    pmS[grp][j] = m; psS[grp][j] = s;
    __syncthreads();
    if (grp == 0) {
      for (int g2 = 1; g2 < 4; ++g2) {
        float m2 = pmS[g2][j], s2 = psS[g2][j];
        if (m2 > m) { s = s * __expf(m - m2) + s2; m = m2; }
        else        { s += s2 * __expf(m2 - m); }
      }
      mS[j] = m; rsS[j] = 1.0f / s;
    }
    __syncthreads();
    int i = t >> 4, j4 = (t & 15) << 2;
    f4a16 mc = *(const f4a16*)&mS[j4];
    f4a16 rs = *(const f4a16*)&rsS[j4];
#pragma unroll
    for (int r = 0; r < 4; ++r) {
      int al = r * 16 + i;
      int a = a0 + al;
      const float* row = Yp + ((size_t)a << 12);
      int b = b0 + j4;
      f4u y = *(const f4u*)(row + b);
      if (a > 0) {
        f4u u_;
        if (b == 0) { f4u rr = *(const f4u*)(row - 4096); u_ = (f4u){0.f, rr.x, rr.y, rr.z}; }
        else u_ = *(const f4u*)(row - 4096 + b - 1);
        y += u_;
      }
      if (a < 4095) {
        f4u d = *(const f4u*)(row + 4096 + b + 1);
        if (b == 4092) d.w = 0.f;
        y += d;
      }
      float g = mmp[a];
      f4u x = y * (10.0f * g);
#pragma unroll
      for (int l = 0; l < 4; ++l)
        T[al][j4 + l] = g * __expf(x[l] - mc[l]) * rs[l];
    }
    __syncthreads();
    int by0 = b0 >> 6;
    int cgrp = (t & 7) * 8;
#pragma unroll
    for (int pass = 0; pass < 2; ++pass) {
      int bl = pass * 32 + (t >> 3);
      int q = bl * 64 + by0;                   // pi(b0 + bl)
      uint4 w;
      w.x = (unsigned)f2bf(T[cgrp + 0][bl]) | ((unsigned)f2bf(T[cgrp + 1][bl]) << 16);
      w.y = (unsigned)f2bf(T[cgrp + 2][bl]) | ((unsigned)f2bf(T[cgrp + 3][bl]) << 16);
      w.z = (unsigned)f2bf(T[cgrp + 4][bl]) | ((unsigned)f2bf(T[cgrp + 5][bl]) << 16);
      w.w = (unsigned)f2bf(T[cgrp + 6][bl]) | ((unsigned)f2bf(T[cgrp + 7][bl]) << 16);
      *(uint4*)(AT + ((size_t)q << 12) + a0 + cgrp) = w;
    }
  } else {
    int k2 = gx - 4096;
    int c = k2 >> 4, dy = (k2 >> 2) & 3, dx = k2 & 3;
    int px = t & 63;
#pragma unroll
    for (int r = 0; r < 16; ++r) {
      int py = r * 4 + (t >> 6);
      int sy = 2 * py + dy - 1, sx = 2 * px + dx - 1;
      float v = 0.f;
      if ((unsigned)sy < (unsigned)HF && (unsigned)sx < (unsigned)WF)
        v = bimg[c * 16384 + sy * 128 + sx];
      T[py][px] = v;
    }
    __syncthreads();
    ushort* orow = VtT + (size_t)k2 * 4096;
#pragma unroll
    for (int r = 0; r < 16; ++r) {
      int a = r * 256 + t;
      orow[a] = f2bf(T[a & 63][a >> 6]);
    }
  }
}

// scatter M[(c,dy,dx), q] -> out (transposed conv, lhs_dilation=2), /4
// reads BOTH split-K halves (Ma + Mb). XCD-swizzled (consecutive blocks share
// M row segments).
__global__ __launch_bounds__(256) void k_scatter(const float* __restrict__ Ma,
                                                 const float* __restrict__ Mb,
                                                 float* __restrict__ out) {
  int bid = ((blockIdx.x & 7) << 10) | (blockIdx.x >> 3);  // bijective, 8192 % 8 == 0
  int idx = bid * 256 + threadIdx.x;
  int ox = idx & 127, oy = (idx >> 7) & 127, c = idx >> 14;
  int qy[2], dyv[2], qx[2], dxv[2];
  if (oy & 1) { qy[0] = (oy - 1) >> 1; dyv[0] = 2; qy[1] = (oy + 1) >> 1; dyv[1] = 0; }
  else        { qy[0] = (oy >> 1) - 1; dyv[0] = 3; qy[1] = oy >> 1;       dyv[1] = 1; }
  if (ox & 1) { qx[0] = (ox - 1) >> 1; dxv[0] = 2; qx[1] = (ox + 1) >> 1; dxv[1] = 0; }
  else        { qx[0] = (ox >> 1) - 1; dxv[0] = 3; qx[1] = ox >> 1;       dxv[1] = 1; }
  float s = 0.f;
#pragma unroll
  for (int i = 0; i < 2; ++i) {
    if ((unsigned)qy[i] >= 64u) continue;
#pragma unroll
    for (int j = 0; j < 2; ++j) {
      if ((unsigned)qx[j] >= 64u) continue;
      int k = c * 16 + dyv[i] * 4 + dxv[j];
      size_t off = (size_t)k * NP + qy[i] * 64 + qx[j];
      s += Ma[off] + Mb[off];
    }
  }
  out[idx] = 0.25f * s;
}

// ---------------------------------------------------------------------------
extern "C" void kernel_launch(void* const* d_in, const int* in_sizes, int n_in,
                              void* d_out, int out_size, void* d_ws, size_t ws_size,
                              hipStream_t stream) {
  const float* f_all = (const float*)d_in[0];
  const float* b_all = (const float*)d_in[1];
  const float* m_all = (const float*)d_in[2];
  float* out = (float*)d_out;

  float* ws = (float*)d_ws;
  float* bufD = ws;                          // 64MB: D -> Yp -> {M0, M1}
  float* bufS = ws + 16777216;               // 64MB: {fcat,bcat} -> S0 -> {AT, VtT}
  ushort* fcat = (ushort*)bufS;
  ushort* bcat = (ushort*)(bufS + 786432);
  float* S0  = bufS;
  float* Yp  = bufD;
  ushort* AT  = (ushort*)bufS;               // 32MB
  ushort* VtT = (ushort*)(bufS + 8388608);   // 16MB
  float* M0 = bufD;                          // 32MB (clobbers Yp)
  float* M1 = bufD + 8388608;                // 32MB
  float* smalls = ws + 2 * 16777216;
  float* s2    = smalls;
  float* rnrm  = s2 + 4096;
  float* mmp   = rnrm + 4096;
  float* pm    = mmp + 4096;
  float* ps    = pm + NCHUNK * NP;

  const size_t zsF = (size_t)CDIM * HF * WF;
  const size_t zsM = (size_t)HF * WF;

  for (int it = 0; it < 2; ++it) {
    const float* f = f_all + it * zsF;
    const float* b = b_all + it * zsF;
    const float* mk = m_all + it * zsM;
    float* o = out + it * zsF;

    k_prep<<<2048, 256, 0, stream>>>(f, b, fcat, bcat, s2);
    k_mmpnorm<<<32, 256, 0, stream>>>(mk, s2, mmp, rnrm);
    // D[p,q] (fp32-accurate via split-bf16, K=384): 256x256 tiles, 256 blocks
    k_mfma_gemm<<<dim3(16, 16, 1), 512, 0, stream>>>(bcat, fcat, bufD, 384, 384, 384, NP, 0);
    k_s0<<<4096, 256, 0, stream>>>(bufD, rnrm, S0);
    k_fuse1<<<4096, 256, 0, stream>>>(S0, Yp);
    k_smax_part<<<dim3(4, NCHUNK), 256, 0, stream>>>(Yp, mmp, pm, ps);
    k_epilogue<<<6144, 256, 0, stream>>>(Yp, pm, ps, mmp, AT, b, VtT);
    // M[k2,q] = sum_a VtT[k2,a] * AT[q,a]  (K=4096, split-K=2 -> 256 blocks)
    k_mfma_gemm<<<dim3(16, 8, 2), 512, 0, stream>>>(VtT, AT, M0, 2048, NP, NP, NP,
                                                    (long)2048 * 4096);
    k_scatter<<<8192, 256, 0, stream>>>(M0, M1, o);
  }
}